// Round 12
// baseline (47.238 us; speedup 1.0000x reference)
//
#include <hip/hip_runtime.h>
#include <math.h>

#define COND_C 6
#define NOUT 11   // N_MODES*DIM*2 + N_MODES + 1

typedef float f32x2 __attribute__((ext_vector_type(2)));

static constexpr float LOG2E         = 1.44269504088896340736f;
static constexpr float LN2           = 0.69314718055994530942f;
static constexpr float INV_2PI       = 0.15915494309189533577f;
static constexpr float NEG_HALF_L2E  = -0.72134752044448170368f;  // -0.5*log2(e)
static constexpr float INV_PI        = 0.31830988618f;

// DUPLICATED packed-weight layout in d_ws (floats) — every weight stored
// twice adjacent so a f32x2 load is a native 64-bit uniform read (SGPR pair,
// the exact v_pk_fma_f32 source shape):
//   [0..511]      W1D: j (32 rows) x 16: {w0,w0,w1,w1,...,w5,w5,b1j,b1j,0,0}
//   [512..1279]   W2D: j (32 rows) x 24: {W2[j][0],W2[j][0],...,W2[j][10],W2[j][10],0,0}
//   [1280..1303]  B2D: {b2[0],b2[0],...,b2[10],b2[10],0,0}
#define WS_W2_OFF 512
#define WS_B2_OFF 1280
#define WS_FLOATS 1312

__device__ __forceinline__ float rcp_f(float x)  { return __builtin_amdgcn_rcpf(x); }
__device__ __forceinline__ float exp2_f(float x) { return __builtin_amdgcn_exp2f(x); }
__device__ __forceinline__ float log2_f(float x) { return __builtin_amdgcn_logf(x); }
__device__ __forceinline__ float sqrt_f(float x) { return __builtin_amdgcn_sqrtf(x); }
// v_sin_f32 / v_cos_f32 take input in REVOLUTIONS: sin_rev(x) = sin(2*pi*x)
__device__ __forceinline__ float sin_rev(float x) { return __builtin_amdgcn_sinf(x); }
__device__ __forceinline__ float cos_rev(float x) { return __builtin_amdgcn_cosf(x); }

__device__ __forceinline__ f32x2 fma2(f32x2 a, f32x2 b, f32x2 c) {
    return __builtin_elementwise_fma(a, b, c);
}

struct RowOut { float z0, z1, lp; };

// Per-row epilogue: sampling + log-density (product form, merged trig).
__device__ __forceinline__ RowOut epilogue(const float* o, float rdn, float u1)
{
    float loc00 = o[0], loc01 = o[1], loc10 = o[2], loc11 = o[3];
    float ls00  = o[4], ls01  = o[5], ls10  = o[6], ls11  = o[7];
    float aw0 = fabsf(o[8]), aw1 = fabsf(o[9]), aw2 = fabsf(o[10]);
    float rinv = rcp_f(aw0 + aw1 + aw2);
    float w0 = aw0 * rinv, w1 = aw1 * rinv, w2 = aw2 * rinv;

    float wc0 = w0;
    float wc1 = w0 + w1;
    bool g1 = rdn < wc0;
    bool g2 = (!g1) && (rdn < wc1);
    bool gauss = g1 || g2;

    float num = rdn - (g1 ? 0.0f : (g2 ? wc0 : wc1));
    float den = g1 ? wc0 : (g2 ? w1 : w2);
    float u0  = num * rcp_f(den);

    // Box-Muller radius (gauss only; harmless otherwise)
    float U1 = gauss ? u0 : 0.5f;
    float R = sqrt_f(-1.38629436111989062f * log2_f(U1));  // sqrt(-2 ln U1)

    // Lambert geometry
    float wo0 = fmaf(2.0f, u0, -1.0f);
    float wo1 = fmaf(2.0f, u1, -1.0f);
    bool c1b = (fabsf(wo0) > fabsf(wo1)) && !((wo0 == 0.0f) && (wo1 == 0.0f));
    float sden = c1b ? wo0 : ((wo1 == 0.0f) ? 1.0f : wo1);
    float rnum = c1b ? wo1 : wo0;
    float r = rnum * rcp_f(sden);
    float a_rev = c1b ? (0.125f * r) : fmaf(-0.125f, r, 0.25f);
    float amp = c1b ? wo0 : wo1;   // both-zero -> amp = 0 -> z = 0

    // merged trig: gauss angle = u1 rev; lambert angle = a_rev
    float angle = gauss ? u1 : a_rev;
    float ca = cos_rev(angle);
    float sa = sin_rev(angle);

    // inverse scales (needed for density anyway)
    float ie00 = exp2_f(-ls00 * LOG2E), ie01 = exp2_f(-ls01 * LOG2E);
    float ie10 = exp2_f(-ls10 * LOG2E), ie11 = exp2_f(-ls11 * LOG2E);

    // z = A*{cos,sin}(angle) + B
    float scale0 = rcp_f(g2 ? ie10 : ie00);   // exp(ls_sel0)
    float scale1 = rcp_f(g2 ? ie11 : ie01);
    float A0 = gauss ? (R * scale0) : amp;
    float A1 = gauss ? (R * scale1) : amp;
    float B0 = gauss ? (g2 ? loc10 : loc00) : 0.0f;
    float B1 = gauss ? (g2 ? loc11 : loc01) : 0.0f;
    float z0 = fmaf(A0, ca, B0);
    float z1 = fmaf(A1, sa, B1);

    // log density, product form
    float e00 = (z0 - loc00) * ie00;
    float e01 = (z1 - loc01) * ie01;
    float e10 = (z0 - loc10) * ie10;
    float e11 = (z1 - loc11) * ie11;
    float q0 = fmaf(e00, e00, e01 * e01);
    float q1 = fmaf(e10, e10, e11 * e11);
    float p0 = (w0 + 1e-5f) * INV_2PI * (ie00 * ie01) * exp2_f(NEG_HALF_L2E * q0);
    float p1 = (w1 + 1e-5f) * INV_2PI * (ie10 * ie11) * exp2_f(NEG_HALF_L2E * q1);
    bool invalid = fmaf(z0, z0, z1 * z1) > 1.0f;
    float pl = invalid ? 1e-5f : (INV_PI + 1e-5f);
    float p2 = pl * w2;

    RowOut out;
    out.z0 = z0; out.z1 = z1;
    out.lp = log2_f(p0 + p1 + p2) * LN2;
    return out;
}

// ---- setup: repack weights (DUPLICATED) into d_ws ----
__global__ void pack_weights_kernel(const float* __restrict__ W1,
                                    const float* __restrict__ b1,
                                    const float* __restrict__ W2,
                                    const float* __restrict__ b2,
                                    float* __restrict__ ws)
{
    for (int idx = threadIdx.x; idx < WS_FLOATS; idx += blockDim.x) {
        float v;
        if (idx < WS_W2_OFF) {                 // W1D: ws[j*16 + c*2 + d]
            int j = idx >> 4;
            int c = (idx & 15) >> 1;
            v = (c < 6) ? W1[c * 32 + j] : ((c == 6) ? b1[j] : 0.0f);
        } else if (idx < WS_B2_OFF) {          // W2D: ws[512 + j*24 + k*2 + d]
            int u = idx - WS_W2_OFF;
            int j = u / 24;
            int k = (u - j * 24) >> 1;
            v = (k < 11) ? W2[j * 11 + k] : 0.0f;
        } else {                               // B2D
            int k = (idx - WS_B2_OFF) >> 1;
            v = (k < 11) ? b2[k] : 0.0f;
        }
        ws[idx] = v;
    }
}

__global__ __launch_bounds__(256)
void gmm_weighted_cond_kernel(const float* __restrict__ cond,
                              const float* __restrict__ seed,
                              const float* __restrict__ ws,
                              float* __restrict__ z_out,
                              float* __restrict__ logp_out,
                              int Npairs)
{
    int t = blockIdx.x * blockDim.x + threadIdx.x;
    if (t >= Npairs) return;

    const f32x2* W1D = reinterpret_cast<const f32x2*>(ws);                // 8 f32x2 per j
    const f32x2* W2D = reinterpret_cast<const f32x2*>(ws + WS_W2_OFF);    // 12 f32x2 per j
    const f32x2* B2D = reinterpret_cast<const f32x2*>(ws + WS_B2_OFF);    // 12 f32x2

    // ---- load 2 rows of cond + seeds up-front ----
    const float4* cp = reinterpret_cast<const float4*>(cond) + (size_t)t * 3;
    float4 ca = cp[0], cb = cp[1], cc = cp[2];
    float4 sd = reinterpret_cast<const float4*>(seed)[t];

    // row A: ca.x ca.y ca.z ca.w cb.x cb.y ; row B: cb.z cb.w cc.x cc.y cc.z cc.w
    f32x2 x0 = {ca.x, cb.z}, x1 = {ca.y, cb.w}, x2 = {ca.z, cc.x};
    f32x2 x3 = {ca.w, cc.y}, x4 = {cb.x, cc.z}, x5 = {cb.y, cc.w};

    // ---- MLP: ROLLED j-loop. All weight operands are 64-bit uniform loads
    // (duplicated pairs) -> SGPR pairs -> direct v_pk_fma_f32 sources. ----
    f32x2 o[NOUT];
#pragma unroll
    for (int k = 0; k < NOUT; ++k) o[k] = B2D[k];

#pragma unroll 1
    for (int j = 0; j < 32; ++j) {
        const f32x2* w1 = W1D + j * 8;
        f32x2 acc = w1[6];             // {b1[j], b1[j]}
        acc = fma2(x0, w1[0], acc);
        acc = fma2(x1, w1[1], acc);
        acc = fma2(x2, w1[2], acc);
        acc = fma2(x3, w1[3], acc);
        acc = fma2(x4, w1[4], acc);
        acc = fma2(x5, w1[5], acc);
        acc = __builtin_elementwise_max(acc, (f32x2){0.0f, 0.0f});

        const f32x2* w2 = W2D + j * 12;
        o[0]  = fma2(acc, w2[0],  o[0]);
        o[1]  = fma2(acc, w2[1],  o[1]);
        o[2]  = fma2(acc, w2[2],  o[2]);
        o[3]  = fma2(acc, w2[3],  o[3]);
        o[4]  = fma2(acc, w2[4],  o[4]);
        o[5]  = fma2(acc, w2[5],  o[5]);
        o[6]  = fma2(acc, w2[6],  o[6]);
        o[7]  = fma2(acc, w2[7],  o[7]);
        o[8]  = fma2(acc, w2[8],  o[8]);
        o[9]  = fma2(acc, w2[9],  o[9]);
        o[10] = fma2(acc, w2[10], o[10]);
    }

    float oA[NOUT], oB[NOUT];
#pragma unroll
    for (int k = 0; k < NOUT; ++k) { oA[k] = o[k].x; oB[k] = o[k].y; }

    RowOut rA = epilogue(oA, sd.x, sd.y);
    RowOut rB = epilogue(oB, sd.z, sd.w);

    // ---- stores: z (N,2) as float4 per pair, log_p as float2 ----
    reinterpret_cast<float4*>(z_out)[t] = make_float4(rA.z0, rA.z1, rB.z0, rB.z1);
    reinterpret_cast<float2*>(logp_out)[t] = make_float2(rA.lp, rB.lp);
}

extern "C" void kernel_launch(void* const* d_in, const int* in_sizes, int n_in,
                              void* d_out, int out_size, void* d_ws, size_t ws_size,
                              hipStream_t stream)
{
    const float* cond = (const float*)d_in[0];
    const float* seed = (const float*)d_in[1];
    const float* W1   = (const float*)d_in[2];
    const float* b1   = (const float*)d_in[3];
    const float* W2   = (const float*)d_in[4];
    const float* b2   = (const float*)d_in[5];

    int N = in_sizes[1] / 2;   // randseed is (N,2)
    int Npairs = N / 2;

    float* ws = (float*)d_ws;
    float* z_out    = (float*)d_out;                   // first 2N floats
    float* logp_out = (float*)d_out + 2 * (size_t)N;   // next N floats

    pack_weights_kernel<<<1, 256, 0, stream>>>(W1, b1, W2, b2, ws);

    int block = 256;
    int grid = (Npairs + block - 1) / block;
    gmm_weighted_cond_kernel<<<grid, block, 0, stream>>>(
        cond, seed, ws, z_out, logp_out, Npairs);
}